// Round 1
// 298.122 us; speedup vs baseline: 1.0480x; 1.0480x over previous
//
#include <hip/hip_runtime.h>
#include <stdint.h>

typedef unsigned short ushort_t;
typedef __bf16 bf16x8 __attribute__((ext_vector_type(8)));
typedef float f32x4 __attribute__((ext_vector_type(4)));
typedef ushort_t us4 __attribute__((ext_vector_type(4)));

#define MFMA16(a, b, c) __builtin_amdgcn_mfma_f32_16x16x32_bf16((a), (b), (c), 0, 0, 0)

constexpr int Bn = 4, Sn = 2048, Dn = 1024, Hn = 16, HDn = 64;
constexpr float SCALE = 0.125f;   // 1/sqrt(64)
constexpr float NEG = -1e9f;

__device__ __forceinline__ float bf2f(ushort_t u) {
  unsigned x = ((unsigned)u) << 16;
  return __builtin_bit_cast(float, x);
}
__device__ __forceinline__ ushort_t f2bf(float f) {
  unsigned x = __builtin_bit_cast(unsigned, f);
  x = x + 0x7FFFu + ((x >> 16) & 1u);   // RNE
  return (ushort_t)(x >> 16);
}
__device__ __forceinline__ uint4 ld8_f32_bf16(const float* __restrict__ p) {
  float4 a = *(const float4*)p;
  float4 b = *(const float4*)(p + 4);
  union { ushort_t u[8]; uint4 v; } r;
  r.u[0] = f2bf(a.x); r.u[1] = f2bf(a.y); r.u[2] = f2bf(a.z); r.u[3] = f2bf(a.w);
  r.u[4] = f2bf(b.x); r.u[5] = f2bf(b.y); r.u[6] = f2bf(b.z); r.u[7] = f2bf(b.w);
  return r.v;
}
// async global->LDS, 16B per lane; LDS dest = wave-uniform base + lane*16
__device__ __forceinline__ void gl2lds16(const void* g, void* l) {
  __builtin_amdgcn_global_load_lds(
      (__attribute__((address_space(1))) void*)g,
      (__attribute__((address_space(3))) void*)l, 16, 0, 0);
}

// One-shot conversion of all f32 inputs to bf16: 3 X (4096 blocks each) then
// 4 W (512 blocks each). Xd: 3x8388608 elems contiguous; Wd: 4x1048576.
__global__ __launch_bounds__(256)
void cvt_all(const float* __restrict__ xq, const float* __restrict__ xk,
             const float* __restrict__ xv, const float* __restrict__ wq,
             const float* __restrict__ wk, const float* __restrict__ wv,
             const float* __restrict__ wo, ushort_t* __restrict__ Xd,
             ushort_t* __restrict__ Wd) {
  const int bid = blockIdx.x;
  if (bid < 12288) {
    const int which = bid >> 12;
    const float* s = which == 0 ? xq : which == 1 ? xk : xv;
    size_t i = ((size_t)(bid & 4095) * 256 + threadIdx.x) * 8;
    *(uint4*)(Xd + (size_t)which * 8388608 + i) = ld8_f32_bf16(s + i);
  } else {
    const int wb = bid - 12288, which = wb >> 9;
    const float* s = which == 0 ? wq : which == 1 ? wk : which == 2 ? wv : wo;
    size_t i = ((size_t)(wb & 511) * 256 + threadIdx.x) * 8;
    *(uint4*)(Wd + (size_t)which * 1048576 + i) = ld8_f32_bf16(s + i);
  }
}

// Fused Q/K/V projections: z = 0/1/2 selects X, W, bias, dst, epilogue.
// Grid (x=row-block, y=col-block): blocks sharing an A row-tile have linear
// IDs spaced 64 (≡ same mod 8) -> same XCD -> row-tile fetched once per L2.
// z=0: Q scatter [B,H,S,HD] b16. z=1,2: transposed scatter [B,H,HD,S] b64.
__global__ __launch_bounds__(256, 4)
void gemm_qkv(const ushort_t* __restrict__ Xb, const ushort_t* __restrict__ Wb,
              const float* __restrict__ bq, const float* __restrict__ bk,
              const float* __restrict__ bv, ushort_t* __restrict__ Qd,
              ushort_t* __restrict__ Ktd, ushort_t* __restrict__ Vtd) {
  constexpr int K = 1024;
  __shared__ __align__(16) ushort_t As[128 * 64];
  __shared__ __align__(16) ushort_t Bs[128 * 64];

  const int z = blockIdx.z;
  const ushort_t* A  = Xb + (size_t)z * 8388608;
  const ushort_t* Wt = Wb + (size_t)z * 1048576;
  const float* bias = z == 0 ? bq : z == 1 ? bk : bv;
  ushort_t* Cp = z == 0 ? Qd : z == 1 ? Ktd : Vtd;

  const int tid = threadIdx.x;
  const int lane = tid & 63, w = tid >> 6;
  const int quad = lane >> 4, l16 = lane & 15;
  const int wm = w >> 1, wn = w & 1;
  const int row0 = blockIdx.x * 128;   // x = row (XCD co-location)
  const int col0 = blockIdx.y * 128;   // y = col

  const int sr = lane >> 3;
  const int sg = ((lane & 7) ^ (sr & 7)) * 8;
  const ushort_t* Ab = A  + (size_t)(row0 + w * 32 + sr) * K + sg;
  const ushort_t* Bb = Wt + (size_t)(col0 + w * 32 + sr) * K + sg;

  f32x4 acc[4][4] = {};

  for (int k0 = 0; k0 < K; k0 += 64) {
    __syncthreads();
#pragma unroll
    for (int i = 0; i < 4; ++i) {
      gl2lds16(Ab + (size_t)(i * 8) * K + k0, &As[(w * 32 + i * 8) * 64]);
      gl2lds16(Bb + (size_t)(i * 8) * K + k0, &Bs[(w * 32 + i * 8) * 64]);
    }
    __syncthreads();
#pragma unroll
    for (int ks = 0; ks < 2; ++ks) {
      const int kg = ((ks * 4 + quad) ^ (l16 & 7)) * 8;
      bf16x8 af[4], bfr[4];
#pragma unroll
      for (int mt = 0; mt < 4; ++mt)
        af[mt] = *(const bf16x8*)(&As[(wm * 64 + mt * 16 + l16) * 64 + kg]);
#pragma unroll
      for (int nt = 0; nt < 4; ++nt)
        bfr[nt] = *(const bf16x8*)(&Bs[(wn * 64 + nt * 16 + l16) * 64 + kg]);
#pragma unroll
      for (int mt = 0; mt < 4; ++mt)
#pragma unroll
        for (int nt = 0; nt < 4; ++nt)
          acc[mt][nt] = MFMA16(af[mt], bfr[nt], acc[mt][nt]);
    }
  }

#pragma unroll
  for (int mt = 0; mt < 4; ++mt) {
#pragma unroll
    for (int nt = 0; nt < 4; ++nt) {
      const int col = col0 + wn * 64 + nt * 16 + l16;
      const float bv4 = bias[col];
      const int rowb = row0 + wm * 64 + mt * 16 + quad * 4;
      if (z != 0) {          // transposed scatter: [b,h,hd,s], b64 over s
        const int b = rowb >> 11, s = rowb & (Sn - 1);
        const int h = col >> 6, hd = col & 63;
        us4 pk;
#pragma unroll
        for (int r = 0; r < 4; ++r) pk[r] = f2bf(acc[mt][nt][r] + bv4);
        *(us4*)(Cp + ((size_t)((b * Hn + h) * HDn + hd)) * Sn + s) = pk;
      } else {               // Q scatter: [b,h,s,hd]
#pragma unroll
        for (int r = 0; r < 4; ++r) {
          const int row = rowb + r;
          const int b = row >> 11, s = row & (Sn - 1);
          const int h = col >> 6, hd = col & 63;
          Cp[(((size_t)(b * Hn + h) * Sn + s) << 6) + hd] = f2bf(acc[mt][nt][r] + bv4);
        }
      }
    }
  }
}

// Final projection: C[M,N] f32 = A[M,K]bf16 @ W[N,K]^T + bias.
// Grid (x=row, y=col) for the same XCD co-location as gemm_qkv.
__global__ __launch_bounds__(256, 4)
void gemm_out(const ushort_t* __restrict__ A, const ushort_t* __restrict__ Wt,
              const float* __restrict__ bias, float* __restrict__ Cp) {
  constexpr int K = 1024;
  __shared__ __align__(16) ushort_t As[128 * 64];
  __shared__ __align__(16) ushort_t Bs[128 * 64];

  const int tid = threadIdx.x;
  const int lane = tid & 63, w = tid >> 6;
  const int quad = lane >> 4, l16 = lane & 15;
  const int wm = w >> 1, wn = w & 1;
  const int row0 = blockIdx.x * 128;
  const int col0 = blockIdx.y * 128;

  const int sr = lane >> 3;
  const int sg = ((lane & 7) ^ (sr & 7)) * 8;
  const ushort_t* Ab = A  + (size_t)(row0 + w * 32 + sr) * K + sg;
  const ushort_t* Bb = Wt + (size_t)(col0 + w * 32 + sr) * K + sg;

  f32x4 acc[4][4] = {};

  for (int k0 = 0; k0 < K; k0 += 64) {
    __syncthreads();
#pragma unroll
    for (int i = 0; i < 4; ++i) {
      gl2lds16(Ab + (size_t)(i * 8) * K + k0, &As[(w * 32 + i * 8) * 64]);
      gl2lds16(Bb + (size_t)(i * 8) * K + k0, &Bs[(w * 32 + i * 8) * 64]);
    }
    __syncthreads();
#pragma unroll
    for (int ks = 0; ks < 2; ++ks) {
      const int kg = ((ks * 4 + quad) ^ (l16 & 7)) * 8;
      bf16x8 af[4], bfr[4];
#pragma unroll
      for (int mt = 0; mt < 4; ++mt)
        af[mt] = *(const bf16x8*)(&As[(wm * 64 + mt * 16 + l16) * 64 + kg]);
#pragma unroll
      for (int nt = 0; nt < 4; ++nt)
        bfr[nt] = *(const bf16x8*)(&Bs[(wn * 64 + nt * 16 + l16) * 64 + kg]);
#pragma unroll
      for (int mt = 0; mt < 4; ++mt)
#pragma unroll
        for (int nt = 0; nt < 4; ++nt)
          acc[mt][nt] = MFMA16(af[mt], bfr[nt], acc[mt][nt]);
    }
  }

#pragma unroll
  for (int mt = 0; mt < 4; ++mt)
#pragma unroll
    for (int nt = 0; nt < 4; ++nt) {
      const int col = col0 + wn * 64 + nt * 16 + l16;
      const float bv = bias[col];
      const int rowb = row0 + wm * 64 + mt * 16 + quad * 4;
#pragma unroll
      for (int r = 0; r < 4; ++r)
        Cp[(size_t)(rowb + r) * 1024 + col] = acc[mt][nt][r] + bv;
    }
}

// Per-tile outer products, fully parallel (replaces the serial half of
// prefixz): G_t[n_v][d_k] = sum_{k in tile t} K[k][d_k]*V[k][n_v]  (f32),
// plus per-tile V row-sums R[bh][t][n] = sum_{k in tile t} V[k][n].
// Grid (x=t 32, y=bh 64) = 2048 blocks -> all CUs busy, latency hidden.
__global__ __launch_bounds__(256)
void gtile(const ushort_t* __restrict__ Kt, const ushort_t* __restrict__ Vt,
           float* __restrict__ Gd, float* __restrict__ Rs) {
  __shared__ __align__(16) ushort_t Kts[4096];
  __shared__ __align__(16) ushort_t Vts[4096];
  __shared__ float tsum[64];
  const int tid = threadIdx.x, lane = tid & 63, w = tid >> 6;
  const int quad = lane >> 4, l16 = lane & 15;
  const int t = blockIdx.x, bh = blockIdx.y;
  const ushort_t* Ktb = Kt + (size_t)bh * HDn * Sn;
  const ushort_t* Vtb = Vt + (size_t)bh * HDn * Sn;

  const int sr = lane >> 3;
  const int sg = ((lane & 7) ^ (sr & 7)) * 8;

  if (tid < 64) tsum[tid] = 0.f;
#pragma unroll
  for (int c = 0; c < 2; ++c) {
    const int row = w * 16 + c * 8;
    gl2lds16(Ktb + (size_t)(row + sr) * Sn + t * 64 + sg, &Kts[row * 64]);
    gl2lds16(Vtb + (size_t)(row + sr) * Sn + t * 64 + sg, &Vts[row * 64]);
  }
  __syncthreads();

  f32x4 zacc[4] = {};
#pragma unroll
  for (int ks = 0; ks < 2; ++ks) {
    const int kg = ((ks * 4 + quad) ^ (l16 & 7)) * 8;
    bf16x8 ak = *(const bf16x8*)(&Kts[(w * 16 + l16) * 64 + kg]);
#pragma unroll
    for (int nt = 0; nt < 4; ++nt) {
      bf16x8 bv8 = *(const bf16x8*)(&Vts[(nt * 16 + l16) * 64 + kg]);
      zacc[nt] = MFMA16(ak, bv8, zacc[nt]);
    }
  }
  float* gd = Gd + (size_t)(bh * 32 + t) * 4096;
#pragma unroll
  for (int nt = 0; nt < 4; ++nt)
    *(f32x4*)(gd + (nt * 16 + l16) * 64 + w * 16 + quad * 4) = zacc[nt];

  // V row partial sums: thread (n = tid&63, j = tid>>6)
  {
    const int n = tid & 63, j = tid >> 6;
    float p = 0.f;
#pragma unroll
    for (int gg2 = 0; gg2 < 2; ++gg2) {
      const int g = 2 * j + gg2;
      union { uint4 v; ushort_t u[8]; } c;
      c.v = *(const uint4*)(&Vts[n * 64 + ((g ^ (n & 7)) << 3)]);
#pragma unroll
      for (int e = 0; e < 8; ++e) p += bf2f(c.u[e]);
    }
    atomicAdd(&tsum[n], p);
  }
  __syncthreads();
  if (tid < 64) Rs[(size_t)(bh * 32 + t) * 64 + tid] = tsum[tid];
}

// Prefix scan over G tiles (register-resident, depth-2 prefetch):
// Z_qt = (1/8) * sum_{t < qt} G_t  (bf16), suffV[t][n] = sum_{tau > t} R[tau][n].
// Grid (x=nc 4, y=bh 64): block owns n-rows [nc*16, nc*16+16) of all 32 tiles;
// 4 f32 accumulators per thread, loads independent of the add chain.
__global__ __launch_bounds__(256)
void scanz(const float* __restrict__ Gd, const float* __restrict__ Rs,
           ushort_t* __restrict__ Zp, float* __restrict__ suffV) {
  const int tid = threadIdx.x;
  const int nc = blockIdx.x, bh = blockIdx.y;
  const int nl = tid >> 4;            // 0..15
  const int n = nc * 16 + nl;
  const int d0 = (tid & 15) * 4;
  const float* gb = Gd + (size_t)bh * 32 * 4096 + n * 64 + d0;
  ushort_t* zb = Zp + (size_t)bh * 32 * 4096 + n * 64 + d0;

  f32x4 acc = {0.f, 0.f, 0.f, 0.f};
  f32x4 g0 = *(const f32x4*)(gb);
  f32x4 g1 = *(const f32x4*)(gb + 4096);
  for (int t = 0; t < 32; ++t) {
    us4 pk;
#pragma unroll
    for (int r = 0; r < 4; ++r) pk[r] = f2bf(SCALE * acc[r]);
    *(us4*)(zb + (size_t)t * 4096) = pk;
    const int tn = (t + 2 < 32) ? t + 2 : 31;   // redundant tail load, in-range
    f32x4 gn = *(const f32x4*)(gb + (size_t)tn * 4096);
    acc += g0;
    g0 = g1; g1 = gn;
  }

  // suffix V row-sums for this block's 16 n values
  __shared__ float rs[32][16];
  for (int i = tid; i < 512; i += 256)
    rs[i >> 4][i & 15] = Rs[(size_t)(bh * 32 + (i >> 4)) * 64 + nc * 16 + (i & 15)];
  __syncthreads();
  if (tid < 16) {
    float a = 0.f;
    for (int t = 31; t >= 0; --t) {
      suffV[(size_t)(bh * 32 + t) * 64 + nc * 16 + tid] = a;
      a += rs[t][tid];
    }
  }
}

// One-shot attention, ONE q-tile per block (grid 64 bh x 32 qt = 2048 blocks).
// Single-buffered; Q fragments loaded global->reg directly (no cross-wave
// reuse), so LDS = Vts+Zs+Ks+Ss = 33 KB -> 4 blocks/CU, 16 waves/CU.
// Per q-tile: O^T = Z'·Q^T + V_d^T·S_d^T  - 1e9*suffV (analytic masked tail).
__global__ __launch_bounds__(256)
void attn_kernel(const ushort_t* __restrict__ Q, const ushort_t* __restrict__ Kt,
                 const ushort_t* __restrict__ Vt, const ushort_t* __restrict__ Zp,
                 const float* __restrict__ suffV, ushort_t* __restrict__ O) {
  __shared__ __align__(16) ushort_t Vts[4096];
  __shared__ __align__(16) ushort_t Zs[4096];
  __shared__ __align__(16) ushort_t Ks[4096];
  __shared__ __align__(16) ushort_t Ss[64][72];

  const int tid = threadIdx.x, lane = tid & 63, w = tid >> 6;
  const int quad = lane >> 4, l16 = lane & 15;
  const int bh = blockIdx.x;
  const int qt = blockIdx.y, q0 = qt * 64;
  const int b = bh >> 4, h = bh & 15;
  const ushort_t* Qb  = Q  + (size_t)bh * Sn * HDn;
  const ushort_t* Ktb = Kt + (size_t)bh * HDn * Sn;
  const ushort_t* Vtb = Vt + (size_t)bh * HDn * Sn;
  const ushort_t* Zb  = Zp + (size_t)(bh * 32 + qt) * 4096;

  const int sr = lane >> 3;
  const int sg = ((lane & 7) ^ (sr & 7)) * 8;
  const int q8 = lane & 7, h8 = lane >> 3;

  // K diagonal tile -> regs first (transpose waits only on these two loads,
  // staging stays in flight underneath)
  uint4 kv[2];
#pragma unroll
  for (int c = 0; c < 2; ++c)
    kv[c] = *(const uint4*)(Ktb + (size_t)(w * 16 + c * 8 + h8) * Sn + q0 + q8 * 8);

#pragma unroll
  for (int c = 0; c < 2; ++c) {
    const int row = w * 16 + c * 8;
    gl2lds16(Vtb + (size_t)(row + sr) * Sn + q0 + sg, &Vts[row * 64]);
    gl2lds16(Zb + (size_t)(row + sr) * 64 + sg, &Zs[row * 64]);
  }

  // Q fragments direct from global (unswizzled; each wave reads its own rows)
  bf16x8 bq[2];
#pragma unroll
  for (int ks = 0; ks < 2; ++ks)
    bq[ks] = *(const bf16x8*)(Qb + (size_t)(q0 + w * 16 + l16) * HDn + (ks * 4 + quad) * 8);

  // transpose-write diagonal K tile (regs -> Ks, rotated+swizzled)
#pragma unroll
  for (int c = 0; c < 2; ++c) {
    const int hd = w * 16 + c * 8 + h8;
    const int G = hd >> 3;
    const ushort_t* ku = (const ushort_t*)&kv[c];
#pragma unroll
    for (int j = 0; j < 8; ++j) {
      const int e = (j + q8) & 7;
      const int s = q8 * 8 + e;
      Ks[s * 64 + ((G ^ e) << 3) + (hd & 7)] = ku[e];
    }
  }
  __syncthreads();   // drains gl2lds (vmcnt) + transpose writes

  f32x4 oacc[4] = {};
#pragma unroll
  for (int ks = 0; ks < 2; ++ks) {        // prefix: O^T += Z' · Q^T
    const int kg = ((ks * 4 + quad) ^ (l16 & 7)) * 8;
#pragma unroll
    for (int nt = 0; nt < 4; ++nt) {
      bf16x8 az = *(const bf16x8*)(&Zs[(nt * 16 + l16) * 64 + kg]);
      oacc[nt] = MFMA16(az, bq[ks], oacc[nt]);
    }
  }
  f32x4 sacc[4] = {};
#pragma unroll
  for (int ks = 0; ks < 2; ++ks) {        // diagonal: S^T = K_d · Q^T
    const int kg = ((ks * 4 + quad) ^ (l16 & 7)) * 8;
#pragma unroll
    for (int nt = 0; nt < 4; ++nt) {
      bf16x8 ak = *(const bf16x8*)(&Ks[(nt * 16 + l16) * 64 + kg]);
      sacc[nt] = MFMA16(ak, bq[ks], sacc[nt]);
    }
  }
  const int qrel = w * 16 + l16;          // mask + scale -> Ss (b64, intra-wave)
#pragma unroll
  for (int nt = 0; nt < 4; ++nt) {
    const int kb = nt * 16 + quad * 4;
    us4 pk;
#pragma unroll
    for (int r = 0; r < 4; ++r) {
      float val = (kb + r > qrel) ? NEG : sacc[nt][r] * SCALE;
      pk[r] = f2bf(val);
    }
    *(us4*)(&Ss[qrel][kb]) = pk;
  }
#pragma unroll
  for (int ks = 0; ks < 2; ++ks) {        // O^T += V_d^T · S_d^T
    bf16x8 bs = *(const bf16x8*)(&Ss[qrel][ks * 32 + quad * 8]);
#pragma unroll
    for (int nt = 0; nt < 4; ++nt) {
      bf16x8 av = *(const bf16x8*)(&Vts[(nt * 16 + l16) * 64 + (((ks * 4 + quad) ^ (l16 & 7)) << 3)]);
      oacc[nt] = MFMA16(av, bs, oacc[nt]);
    }
  }

  // masked tail + store O[b,s,d] (b64 over n)
  const float* sv = suffV + (size_t)(bh * 32 + qt) * 64;
  const int s = q0 + w * 16 + l16;
#pragma unroll
  for (int nt = 0; nt < 4; ++nt) {
    const int nb = nt * 16 + quad * 4;
    float4 s4 = *(const float4*)(sv + nb);
    us4 pk;
    pk[0] = f2bf(oacc[nt][0] + NEG * s4.x);
    pk[1] = f2bf(oacc[nt][1] + NEG * s4.y);
    pk[2] = f2bf(oacc[nt][2] + NEG * s4.z);
    pk[3] = f2bf(oacc[nt][3] + NEG * s4.w);
    *(us4*)(&O[((size_t)(b * Sn + s)) * Dn + h * 64 + nb]) = pk;
  }
}

extern "C" void kernel_launch(void* const* d_in, const int* in_sizes, int n_in,
                              void* d_out, int out_size, void* d_ws, size_t ws_size,
                              hipStream_t stream) {
  const float* Xq = (const float*)d_in[0];
  const float* Xk = (const float*)d_in[1];
  const float* Xv = (const float*)d_in[2];
  // d_in[3]: causal mask (int32) — tril, handled analytically
  const float* Wq = (const float*)d_in[4];
  const float* bq = (const float*)d_in[5];
  const float* Wk = (const float*)d_in[6];
  const float* bk = (const float*)d_in[7];
  const float* Wv = (const float*)d_in[8];
  const float* bv = (const float*)d_in[9];
  const float* Wo = (const float*)d_in[10];
  const float* bo = (const float*)d_in[11];

  // ws (MiB): [0,48) Xb(3) | [48,56) Wb(4) | [56,72) Q | [72,88) Kt |
  // [88,104) Vt | [104,120) Z | [120,136) O | [136,136.5) suffV |
  // [144,176) G f32 | [176,176.5) R f32          (d_ws = 256 MiB)
  constexpr size_t MiB = 1024 * 1024;
  char* ws = (char*)d_ws;
  ushort_t* Xb  = (ushort_t*)(ws);
  ushort_t* Wb  = (ushort_t*)(ws + 48 * MiB);
  ushort_t* Qb  = (ushort_t*)(ws + 56 * MiB);
  ushort_t* Ktb = (ushort_t*)(ws + 72 * MiB);
  ushort_t* Vtb = (ushort_t*)(ws + 88 * MiB);
  ushort_t* Zp  = (ushort_t*)(ws + 104 * MiB);
  ushort_t* Ob  = (ushort_t*)(ws + 120 * MiB);
  float*    sV  = (float*)   (ws + 136 * MiB);
  float*    Gd  = (float*)   (ws + 144 * MiB);
  float*    Rsum= (float*)   (ws + 176 * MiB);

  cvt_all<<<14336, 256, 0, stream>>>(Xq, Xk, Xv, Wq, Wk, Wv, Wo, Xb, Wb);
  gemm_qkv<<<dim3(64, 8, 3), 256, 0, stream>>>(Xb, Wb, bq, bk, bv, Qb, Ktb, Vtb);
  gtile<<<dim3(32, 64), 256, 0, stream>>>(Ktb, Vtb, Gd, Rsum);
  scanz<<<dim3(4, 64), 256, 0, stream>>>(Gd, Rsum, Zp, sV);
  attn_kernel<<<dim3(64, 32), 256, 0, stream>>>(Qb, Ktb, Vtb, Zp, sV, Ob);
  gemm_out<<<dim3(64, 8), 256, 0, stream>>>(Ob, Wb + (size_t)3 * 1048576, bo,
                                            (float*)d_out);
}